// Round 6
// baseline (220.713 us; speedup 1.0000x reference)
//
#include <hip/hip_runtime.h>

#define NPTS 131072
#define MNBR 34
#define KP 15
#define CIN 32
#define COUT 64
#define INV_INFL 25.0f          // 1 / POINT_INFLUENCE(0.04)
#define BN_EPS 1e-5f
#define NEG_SLOPE 0.2f
#define PPB 16                  // points per block (2 waves x 8)
#define NBLK (NPTS / PPB)       // 8192 conv blocks
#define NBIN 512                // stat bins (16 blocks per bin)

typedef unsigned short u16;
typedef unsigned int u32;
typedef short short8 __attribute__((ext_vector_type(8)));   // 8 bf16 (4 VGPRs)
typedef float f32x4 __attribute__((ext_vector_type(4)));

static __device__ __forceinline__ u16 f2bf(float f) {       // RNE
    u32 x = __float_as_uint(f);
    x += 0x7fffu + ((x >> 16) & 1u);
    return (u16)(x >> 16);
}
static __device__ __forceinline__ u32 pk2bf(float lo, float hi) {  // round-half-up pack
    u32 a = __float_as_uint(lo) + 0x8000u;
    u32 b = __float_as_uint(hi) + 0x8000u;
    return (a >> 16) | (b & 0xffff0000u);
}

// ws layout (bytes) — total 10.38 MB
#define WS_WT   0u              // u16[64*480]          = 61440
#define WS_SCSH 65536u          // f32[128]
#define WS_SP   131072u         // f32[64*512]          = 131072 (atomic bins)
#define WS_QP   262144u         // f32[64*512]          = 131072 (contiguous after SP)
#define WS_XY   393216u         // float4[NPTS+1]       = 2097168 (xyz padded + shadow row)
#define WS_FB   2490624u        // u16[(NPTS+1)*32]     = 8388672 bf16 feats + zero shadow row

// prep: WT transpose, XY padded xyz table, FB bf16 table, zero stat bins
__global__ __launch_bounds__(256) void prep(const float* __restrict__ Wg,
                                            const float* __restrict__ feats,
                                            const float* __restrict__ xyz,
                                            u16* __restrict__ WT, float4* __restrict__ XY,
                                            u32* __restrict__ FBu, float* __restrict__ SpQp) {
    int b = blockIdx.x;
    if (b < 120) {
        int i2 = b * 256 + threadIdx.x;          // < 30720
        WT[(i2 & 63) * 480 + (i2 >> 6)] = f2bf(Wg[i2]);
    } else if (b < 633) {
        int r = (b - 120) * 256 + threadIdx.x;
        if (r <= NPTS) {
            float4 v;
            if (r < NPTS) v = make_float4(xyz[3 * r], xyz[3 * r + 1], xyz[3 * r + 2], 0.f);
            else          v = make_float4(1e6f, 1e6f, 1e6f, 0.f);   // shadow -> w = 0
            XY[r] = v;
        }
    } else if (b < 8826) {
        int g = (b - 633) * 256 + threadIdx.x;   // u32 index into FB
        if (g < ((NPTS + 1) * CIN) / 2) {
            int e = g * 2;
            u32 v = 0;
            if (e < NPTS * CIN)
                v = (u32)f2bf(feats[e]) | ((u32)f2bf(feats[e + 1]) << 16);
            FBu[g] = v;                          // row NPTS -> zeros (shadow)
        }
    } else {
        SpQp[(b - 8826) * 256 + threadIdx.x] = 0.f;   // 256 blocks x 256 = 65536 = Sp|Qp
    }
}

__global__ __launch_bounds__(128, 5) void kpconv_conv(
    const float* __restrict__ xyz, const int* __restrict__ nbr,
    const float4* __restrict__ XY, const u32* __restrict__ FBu,
    const u16* __restrict__ WT, const float* __restrict__ kpts,
    float* __restrict__ out, float* __restrict__ Sp, float* __restrict__ Qp)
{
    // ONLY LDS: wf 16 rows x 512 bf16; 16B-unit u of row r at phys (u ^ (r&7))
    // exactly 16384 B -> 10 blocks/CU (20 waves, 62.5% occupancy)
    __shared__ u32 wf[PPB * 256];

    const int tid = threadIdx.x, lane = tid & 63, wave = tid >> 6;
    const int q = lane >> 4, t = lane & 15;
    const int q8 = q * 8;
    const int pbase = blockIdx.x * PPB + wave * 8;

    // per-lane kernel-point constants (k == t): d^2 = (o.a_t + c_t) + |o|^2
    float axt = 0.f, ayt = 0.f, azt = 0.f, ckt = 1e30f;   // t==15 pad -> w=0
    if (t < KP) {
        float kx = kpts[3 * t], ky = kpts[3 * t + 1], kz = kpts[3 * t + 2];
        axt = -2.f * kx; ayt = -2.f * ky; azt = -2.f * kz;
        ckt = fmaf(kx, kx, fmaf(ky, ky, kz * kz));
    }

    auto ldnbr = [&](int pp) {
        int v = NPTS;
        if (lane < MNBR) v = nbr[(size_t)(pbase + pp) * MNBR + lane];
        if ((u32)v > (u32)NPTS) v = NPTS;
        return v;
    };
    // FB loads for a point whose per-lane nbr idx register is ix
    auto ldfb = [&](int ix, u32* fb, u32& d32, u32& d33) {
        #pragma unroll
        for (int j = 0; j < 8; ++j) {
            int rj = __shfl(ix, q8 + j, 64);
            fb[j] = FBu[(size_t)rj * 16 + t];
        }
        int r32 = __builtin_amdgcn_readlane(ix, 32);
        int r33 = __builtin_amdgcn_readlane(ix, 33);
        d32 = FBu[(size_t)r32 * 16 + t];
        d33 = FBu[(size_t)r33 * 16 + t];
    };

    // ---------------- prologue: idx for p=0,1,2; pos for 0,1; FB for 0,1
    int ixC = ldnbr(0), ix1 = ldnbr(1), ix2 = ldnbr(2);
    float4 pnC = XY[ixC];
    float4 pn1 = XY[ix1];
    u32 fbC[8], fb1[8], fb2[8];
    u32 d32C, d33C, d32_1, d33_1, d32_2, d33_2;
    ldfb(ixC, fbC, d32C, d33C);
    ldfb(ix1, fb1, d32_1, d33_1);

    #pragma unroll
    for (int p = 0; p < 8; ++p) {
        // (a) nbr idx for p+3
        int ixN = NPTS;
        if (p < 5) ixN = ldnbr(p + 3);
        // (b) neighbor positions for p+2
        float4 pn2 = make_float4(1e6f, 1e6f, 1e6f, 0.f);
        if (p < 6) pn2 = XY[ix2];
        // (c) FB for p+2 (depends only on nbr idx, not on XY)
        if (p < 6) ldfb(ix2, fb2, d32_2, d33_2);
        else { d32_2 = 0; d33_2 = 0; }

        // (d) compute point p
        const int n = pbase + p;                      // wave-uniform -> scalar loads
        const float qx = xyz[3 * n], qy = xyz[3 * n + 1], qz = xyz[3 * n + 2];
        float ox = pnC.x - qx, oy = pnC.y - qy, oz = pnC.z - qz;
        const float oo = fmaf(ox, ox, fmaf(oy, oy, oz * oz));

        // distribute o-records via bpermute; compute w(k=t, m=q8+j)
        float wj[8];
        #pragma unroll
        for (int j = 0; j < 8; ++j) {
            float oxj = __shfl(ox, q8 + j, 64);
            float oyj = __shfl(oy, q8 + j, 64);
            float ozj = __shfl(oz, q8 + j, 64);
            float ooj = __shfl(oo, q8 + j, 64);
            float d2 = fmaf(oxj, axt, fmaf(oyj, ayt, fmaf(ozj, azt, ckt))) + ooj;
            float dd = __builtin_amdgcn_sqrtf(d2);    // tiny d2<0 -> NaN -> fmax gives 0
            wj[j] = fmaxf(0.f, fmaf(dd, -INV_INFL, 1.f));
        }
        union { short8 v; u32 d[4]; } a1, a2, e1, o1, e2, o2;
        #pragma unroll
        for (int i = 0; i < 4; ++i) a1.d[i] = pk2bf(wj[2 * i], wj[2 * i + 1]);
        {   // tail rows m=32,33 (K-slots 0,1 of a rank-2 step; nonzero only at q==0)
            float oxA = __uint_as_float(__builtin_amdgcn_readlane(__float_as_uint(ox), 32));
            float oyA = __uint_as_float(__builtin_amdgcn_readlane(__float_as_uint(oy), 32));
            float ozA = __uint_as_float(__builtin_amdgcn_readlane(__float_as_uint(oz), 32));
            float ooA = __uint_as_float(__builtin_amdgcn_readlane(__float_as_uint(oo), 32));
            float oxB = __uint_as_float(__builtin_amdgcn_readlane(__float_as_uint(ox), 33));
            float oyB = __uint_as_float(__builtin_amdgcn_readlane(__float_as_uint(oy), 33));
            float ozB = __uint_as_float(__builtin_amdgcn_readlane(__float_as_uint(oz), 33));
            float ooB = __uint_as_float(__builtin_amdgcn_readlane(__float_as_uint(oo), 33));
            float dA = __builtin_amdgcn_sqrtf(fmaf(oxA, axt, fmaf(oyA, ayt, fmaf(ozA, azt, ckt))) + ooA);
            float dB = __builtin_amdgcn_sqrtf(fmaf(oxB, axt, fmaf(oyB, ayt, fmaf(ozB, azt, ckt))) + ooB);
            float wA = fmaxf(0.f, fmaf(dA, -INV_INFL, 1.f));
            float wB = fmaxf(0.f, fmaf(dB, -INV_INFL, 1.f));
            a2.d[0] = (q == 0) ? pk2bf(wA, wB) : 0u;
            a2.d[1] = 0; a2.d[2] = 0; a2.d[3] = 0;
        }
        #pragma unroll
        for (int i = 0; i < 4; ++i) {                 // even/odd channel split via v_perm
            u32 aa = fbC[2 * i], bb2 = fbC[2 * i + 1];
            e1.d[i] = __builtin_amdgcn_perm(bb2, aa, 0x05040100u);  // lo16(a)|lo16(b)<<16
            o1.d[i] = __builtin_amdgcn_perm(bb2, aa, 0x07060302u);  // hi16(a)|hi16(b)<<16
        }
        {
            u32 lo = __builtin_amdgcn_perm(d33C, d32C, 0x05040100u);
            u32 hi = __builtin_amdgcn_perm(d33C, d32C, 0x07060302u);
            e2.d[0] = (q == 0) ? lo : 0u;  e2.d[1] = 0; e2.d[2] = 0; e2.d[3] = 0;
            o2.d[0] = (q == 0) ? hi : 0u;  o2.d[1] = 0; o2.d[2] = 0; o2.d[3] = 0;
        }
        f32x4 c0 = {0.f, 0.f, 0.f, 0.f}, c1 = {0.f, 0.f, 0.f, 0.f};
        c0 = __builtin_amdgcn_mfma_f32_16x16x32_bf16(a1.v, e1.v, c0, 0, 0, 0);
        c0 = __builtin_amdgcn_mfma_f32_16x16x32_bf16(a2.v, e2.v, c0, 0, 0, 0);
        c1 = __builtin_amdgcn_mfma_f32_16x16x32_bf16(a1.v, o1.v, c1, 0, 0, 0);
        c1 = __builtin_amdgcn_mfma_f32_16x16x32_bf16(a2.v, o2.v, c1, 0, 0, 0);

        // D (col=t -> ch 2t/2t+1, row ko=q*4+r) -> swizzled wf row   [R3-verified]
        const int row = wave * 8 + p;
        #pragma unroll
        for (int r = 0; r < 4; ++r) {
            int ko = q * 4 + r;
            u32 pk = pk2bf(c0[r], c1[r]);
            int unit = ko * 4 + (t >> 2);
            wf[row * 256 + ((unit ^ (row & 7)) << 2) + (t & 3)] = pk;
        }

        // rotate pipeline (pure renames after full unroll)
        pnC = pn1; pn1 = pn2;
        ixC = ix1; ix1 = ix2; ix2 = ixN;
        #pragma unroll
        for (int j = 0; j < 8; ++j) { fbC[j] = fb1[j]; fb1[j] = fb2[j]; }
        d32C = d32_1; d33C = d33_1; d32_1 = d32_2; d33_1 = d33_2;
    }
    __syncthreads();

    // -------- Phase B (R4/R5-verified): OUT[16x64] = wf[16x480] @ W[480x64]; 2 col-tiles/wave
    const int wcol0 = (wave * 2 + 0) * 16 + t;
    const int wcol1 = (wave * 2 + 1) * 16 + t;
    f32x4 A0 = {0.f, 0.f, 0.f, 0.f}, A1 = {0.f, 0.f, 0.f, 0.f};
    const u16* wt0 = WT + wcol0 * 480 + q * 8;
    const u16* wt1 = WT + wcol1 * 480 + q * 8;
    #pragma unroll
    for (int ks = 0; ks < KP; ++ks) {
        const int u = ks * 4 + q;
        short8 a   = *(const short8*)&wf[t * 256 + ((u ^ (t & 7)) << 2)];
        short8 bb0 = *(const short8*)(wt0 + ks * 32);
        short8 bb1 = *(const short8*)(wt1 + ks * 32);
        A0 = __builtin_amdgcn_mfma_f32_16x16x32_bf16(a, bb0, A0, 0, 0, 0);
        A1 = __builtin_amdgcn_mfma_f32_16x16x32_bf16(a, bb1, A1, 0, 0, 0);
    }
    const int base = blockIdx.x * PPB;
    float s0 = 0.f, q0 = 0.f, s1 = 0.f, q1 = 0.f;
    #pragma unroll
    for (int r = 0; r < 4; ++r) {
        float v0 = A0[r], v1 = A1[r];
        out[(base + q * 4 + r) * COUT + wcol0] = v0;
        out[(base + q * 4 + r) * COUT + wcol1] = v1;
        s0 += v0; q0 = fmaf(v0, v0, q0);
        s1 += v1; q1 = fmaf(v1, v1, q1);
    }
    s0 += __shfl_xor(s0, 16, 64); s0 += __shfl_xor(s0, 32, 64);
    q0 += __shfl_xor(q0, 16, 64); q0 += __shfl_xor(q0, 32, 64);
    s1 += __shfl_xor(s1, 16, 64); s1 += __shfl_xor(s1, 32, 64);
    q1 += __shfl_xor(q1, 16, 64); q1 += __shfl_xor(q1, 32, 64);
    if (q == 0) {
        const int bin = blockIdx.x >> 4;
        atomicAdd(&Sp[wcol0 * NBIN + bin], s0);
        atomicAdd(&Qp[wcol0 * NBIN + bin], q0);
        atomicAdd(&Sp[wcol1 * NBIN + bin], s1);
        atomicAdd(&Qp[wcol1 * NBIN + bin], q1);
    }
}

// 64 blocks: block = channel; reduce bins -> scale/shift
__global__ __launch_bounds__(256) void bn_reduce(
    const float* __restrict__ Sp, const float* __restrict__ Qp,
    const float* __restrict__ gamma, const float* __restrict__ beta,
    float* __restrict__ scsh)
{
    const int ch = blockIdx.x;
    const int tid = threadIdx.x;
    float s = 0.f, qq = 0.f;
    if (tid < NBIN / 4) {                                // 128 threads carry data
        float4 a = ((const float4*)(Sp + ch * NBIN))[tid]; s  = a.x + a.y + a.z + a.w;
        float4 b = ((const float4*)(Qp + ch * NBIN))[tid]; qq = b.x + b.y + b.z + b.w;
    }
    #pragma unroll
    for (int off = 1; off < 64; off <<= 1) {
        s += __shfl_xor(s, off, 64); qq += __shfl_xor(qq, off, 64);
    }
    __shared__ float red[8];
    const int w = tid >> 6;
    if ((tid & 63) == 0) { red[w * 2] = s; red[w * 2 + 1] = qq; }
    __syncthreads();
    if (tid == 0) {
        s  = red[0] + red[2] + red[4] + red[6];
        qq = red[1] + red[3] + red[5] + red[7];
        float mean = s * (1.0f / NPTS);
        float var  = qq * (1.0f / NPTS) - mean * mean;
        float sc = gamma[ch] * rsqrtf(var + BN_EPS);
        scsh[ch] = sc;
        scsh[64 + ch] = beta[ch] - mean * sc;
    }
}

__global__ __launch_bounds__(256) void bn_apply(
    float* __restrict__ out, const float* __restrict__ scsh)
{
    __shared__ float sc[64], sh[64];
    const int tid = threadIdx.x;
    if (tid < 64) { sc[tid] = scsh[tid]; sh[tid] = scsh[64 + tid]; }
    __syncthreads();
    const int gid = blockIdx.x * 256 + tid;          // 4 f32 per thread
    float4 v = ((const float4*)out)[gid];
    const int c0 = (gid * 4) & 63;
    float y0 = fmaf(v.x, sc[c0 + 0], sh[c0 + 0]);
    float y1 = fmaf(v.y, sc[c0 + 1], sh[c0 + 1]);
    float y2 = fmaf(v.z, sc[c0 + 2], sh[c0 + 2]);
    float y3 = fmaf(v.w, sc[c0 + 3], sh[c0 + 3]);
    float4 w;
    w.x = fmaxf(y0, NEG_SLOPE * y0);
    w.y = fmaxf(y1, NEG_SLOPE * y1);
    w.z = fmaxf(y2, NEG_SLOPE * y2);
    w.w = fmaxf(y3, NEG_SLOPE * y3);
    ((float4*)out)[gid] = w;
}

extern "C" void kernel_launch(void* const* d_in, const int* in_sizes, int n_in,
                              void* d_out, int out_size, void* d_ws, size_t ws_size,
                              hipStream_t stream) {
    (void)in_sizes; (void)n_in; (void)out_size; (void)ws_size;
    const float* xyz   = (const float*)d_in[0];
    const float* feats = (const float*)d_in[1];
    const int*   nbr   = (const int*)d_in[2];
    const float* Wg    = (const float*)d_in[3];
    const float* kpts  = (const float*)d_in[4];
    const float* gamma = (const float*)d_in[5];
    const float* beta  = (const float*)d_in[6];
    float* out = (float*)d_out;
    char* ws = (char*)d_ws;
    u16*    WT   = (u16*)(ws + WS_WT);
    float*  scsh = (float*)(ws + WS_SCSH);
    float*  Sp   = (float*)(ws + WS_SP);
    float*  Qp   = (float*)(ws + WS_QP);
    float4* XY   = (float4*)(ws + WS_XY);
    u32*    FBu  = (u32*)(ws + WS_FB);

    prep<<<dim3(9082), dim3(256), 0, stream>>>(Wg, feats, xyz, WT, XY, FBu, Sp);
    kpconv_conv<<<dim3(NBLK), dim3(128), 0, stream>>>(xyz, nbr, XY, FBu, WT, kpts, out, Sp, Qp);
    bn_reduce<<<dim3(64), dim3(256), 0, stream>>>(Sp, Qp, gamma, beta, scsh);
    bn_apply<<<dim3((NPTS * COUT) / (256 * 4)), dim3(256), 0, stream>>>(out, scsh);
}